// Round 2
// baseline (76.384 us; speedup 1.0000x reference)
//
#include <hip/hip_runtime.h>
#include <math.h>

#define EPSF 1e-9f

// r16 = r15 structure with 4 lanes per instance (lanes 2,3 replicate 0,1).
// Rationale: kernel is latency-bound at exactly 1 wave/SIMD (1024 waves on
// 1024 SIMDs); replicating the lane-pair doubles resident waves to 2/SIMD so
// dependent-chain stalls of one wave are filled by the other. March/clip code
// is unchanged: quad lanes {0,1,2,3} run {even,odd,even,odd} roles; shfl_xor
// pairing (0,1) and (2,3) both serve the same instance; only lane (tid&3)==0
// contributes to the reduction.
__global__ __launch_bounds__(256)
void giou_kernel(const float* __restrict__ pred,
                 const float* __restrict__ target,
                 const float* __restrict__ weight,
                 float* __restrict__ out,
                 int n, float invN) {
    __shared__ float2 HH[9 * 256];            // per-thread hull(P) vert columns
    __shared__ float red[4];
    const int tid = threadIdx.x;
    const int odd = tid & 1;
    const int i0 = blockIdx.x * 64 + (tid >> 2);   // 64 instances / 256-thread block
    const bool valid = i0 < n;
    const int i = valid ? i0 : (n > 0 ? n - 1 : 0);

    // ---- target (4 pts) + instance centering at T centroid ----
    float Tx[4], Ty[4];
    {
        const float4* tp = (const float4*)target + (size_t)i * 2;
        float4 t0 = tp[0], t1 = tp[1];
        Tx[0] = t0.x; Ty[0] = t0.y; Tx[1] = t0.z; Ty[1] = t0.w;
        Tx[2] = t1.x; Ty[2] = t1.y; Tx[3] = t1.z; Ty[3] = t1.w;
    }
    float w_i = weight[i];                    // independent early load
    float ctrx = 0.25f * (Tx[0] + Tx[1] + Tx[2] + Tx[3]);
    float ctry = 0.25f * (Ty[0] + Ty[1] + Ty[2] + Ty[3]);
#pragma unroll
    for (int k = 0; k < 4; k++) { Tx[k] -= ctrx; Ty[k] -= ctry; }

    float saT = 0.5f * ((Tx[0] * Ty[1] - Tx[1] * Ty[0]) + (Tx[1] * Ty[2] - Tx[2] * Ty[1]) +
                        (Tx[2] * Ty[3] - Tx[3] * Ty[2]) + (Tx[3] * Ty[0] - Tx[0] * Ty[3]));
    float areaB = fabsf(saT);
    bool rev = saT < 0.f;
    float tcx[4], tcy[4];     // CCW target (centered)
#pragma unroll
    for (int k = 0; k < 4; k++) {
        tcx[k] = rev ? Tx[3 - k] : Tx[k];
        tcy[k] = rev ? Ty[3 - k] : Ty[k];
    }

    // ---- 13-pt working set (centered, registers) ----
    float X[13], Y[13];
    {
        const float2* pp = (const float2*)pred + (size_t)i * 9;
#pragma unroll
        for (int k = 0; k < 9; k++) {
            float2 v = pp[k];
            X[k] = v.x - ctrx; Y[k] = v.y - ctry;
        }
    }
#pragma unroll
    for (int k = 0; k < 4; k++) {
        X[9 + k] = odd ? Tx[k] : X[0];
        Y[9 + k] = odd ? Ty[k] : Y[0];
    }

    // ---- Jarvis march (CCW), tournament-tree candidate selection ----
    float sxm = X[0], sym = Y[0];
#pragma unroll
    for (int j = 1; j < 13; j++) {
        bool lt = (X[j] < sxm) || ((X[j] == sxm) && (Y[j] < sym));
        sxm = lt ? X[j] : sxm;
        sym = lt ? Y[j] : sym;
    }
    float cx = sxm, cy = sym;
    float area2 = 0.f;
    int h = 0;
    bool done = false;
#pragma unroll 1
    for (int step = 0; step < 13; step++) {
        if (__builtin_amdgcn_ballot_w64(!done) == 0ull) break;   // wave-uniform exit
        float ax[13], ay[13], rx[13], ry[13], dd[13];
#pragma unroll
        for (int j = 0; j < 13; j++) {
            ax[j] = X[j]; ay[j] = Y[j];
            rx[j] = X[j] - cx; ry[j] = Y[j] - cy;
            dd[j] = rx[j] * rx[j] + ry[j] * ry[j];   // 0 -> candidate == cur
        }
        // b beats a iff b valid && (a invalid || b CW of a || collinear+farther)
#define MATCH_(a, b)                                                          \
        {                                                                     \
            float cr_ = rx[a] * ry[b] - ry[a] * rx[b];                        \
            bool bw_ = (dd[b] > 0.f) &&                                       \
                       ((dd[a] == 0.f) || (cr_ < 0.f) ||                      \
                        ((cr_ == 0.f) && (dd[b] > dd[a])));                   \
            ax[a] = bw_ ? ax[b] : ax[a]; ay[a] = bw_ ? ay[b] : ay[a];         \
            rx[a] = bw_ ? rx[b] : rx[a]; ry[a] = bw_ ? ry[b] : ry[a];         \
            dd[a] = bw_ ? dd[b] : dd[a];                                      \
        }
        MATCH_(0, 1)  MATCH_(2, 3)  MATCH_(4, 5)
        MATCH_(6, 7)  MATCH_(8, 9)  MATCH_(10, 11)
        MATCH_(0, 2)  MATCH_(4, 6)  MATCH_(8, 10)
        MATCH_(0, 4)  MATCH_(8, 12)
        MATCH_(0, 8)
#undef MATCH_
        bool bv = dd[0] > 0.f;
        float bx = bv ? ax[0] : cx;
        float by = bv ? ay[0] : cy;
        if (!done) {
            if (!odd && h < 9) HH[h * 256 + tid] = make_float2(cx, cy);
            h++;
            area2 += cx * by - bx * cy;
        }
        done = done || ((bx == sxm) && (by == sym)) || ((bx == cx) && (by == cy));
        cx = bx; cy = by;
    }
    float area = fabsf(0.5f * area2);

    // ---- exchange areas / hull size ----
    float areaO = __shfl_xor(area, 1, 64);
    float areaA = odd ? areaO : area;
    float areaC = odd ? area : areaO;
    int hO = __shfl_xor(h, 1, 64);
    int mA = odd ? hO : h;                    // hull(P) vertex count
    mA = (mA < 9) ? mA : 9;                   // defensive (write guard matches)
    __syncthreads();                          // even-lane hull visible
    const float2* HP = &HH[tid & ~1];         // even column of the pair

    // ---- merged S1/S2: ONE rolled loop over hull(P) edges ----
    float S = 0.f;
    float loT[4] = {0.f, 0.f, 0.f, 0.f}, hiT[4] = {1.f, 1.f, 1.f, 1.f};
#pragma unroll 1
    for (int j = 0; j < mA; j++) {
        float2 a = HP[j * 256];
        int j1 = (j + 1 == mA) ? 0 : j + 1;
        float2 b = HP[j1 * 256];

        // --- S1 for hull edge a->b (Liang-Barsky vs T's 4 CCW planes) ---
        float lo = 0.f, hi = 1.f;
#pragma unroll
        for (int e = 0; e < 4; e++) {
            int e1 = (e + 1) & 3;
            float ex_ = tcx[e1] - tcx[e], ey_ = tcy[e1] - tcy[e];
            float s0 = ex_ * (a.y - tcy[e]) - ey_ * (a.x - tcx[e]);
            float s1 = ex_ * (b.y - tcy[e]) - ey_ * (b.x - tcx[e]);
            bool in0 = s0 >= 0.f, in1 = s1 >= 0.f;
            float den = s0 - s1;
            float ddn = (fabsf(den) < 1e-30f) ? 1e-30f : den;
            float t = s0 / ddn;                  // only used when in0!=in1
            bool crs = (in0 != in1);
            lo = (crs && !in0) ? fmaxf(lo, t) : lo;
            hi = (crs && in0)  ? fminf(hi, t) : hi;
            bool out2 = (!in0 && !in1);
            lo = out2 ? 1.f : lo;                // sticky kill
            hi = out2 ? 0.f : hi;
        }
        float dxe = b.x - a.x, dye = b.y - a.y;
        float A0x = a.x + lo * dxe, A0y = a.y + lo * dye;
        float B0x = a.x + hi * dxe, B0y = a.y + hi * dye;
        float c1_ = A0x * B0y - B0x * A0y;
        S += (lo < hi) ? c1_ : 0.f;

        // --- S2 interval updates for plane (a,b) ---
#pragma unroll
        for (int k = 0; k < 4; k++) {
            int k1 = (k + 1) & 3;
            float s0 = dxe * (tcy[k] - a.y) - dye * (tcx[k] - a.x);
            float s1 = dxe * (tcy[k1] - a.y) - dye * (tcx[k1] - a.x);
            bool in0 = s0 >= 0.f, in1 = s1 >= 0.f;
            float den = s0 - s1;
            float ddn = (fabsf(den) < 1e-30f) ? 1e-30f : den;
            float t = s0 / ddn;
            bool crs = (in0 != in1);
            loT[k] = (crs && !in0) ? fmaxf(loT[k], t) : loT[k];
            hiT[k] = (crs && in0)  ? fminf(hiT[k], t) : hiT[k];
            bool out2 = (!in0 && !in1);
            loT[k] = out2 ? 1.f : loT[k];
            hiT[k] = out2 ? 0.f : hiT[k];
        }
    }
    bool hullOK = (mA >= 3);                    // mA<3: inter == 0 exactly
#pragma unroll
    for (int k = 0; k < 4; k++) {
        int k1 = (k + 1) & 3;
        float dxe = tcx[k1] - tcx[k], dye = tcy[k1] - tcy[k];
        float A0x = tcx[k] + loT[k] * dxe, A0y = tcy[k] + loT[k] * dye;
        float B0x = tcx[k] + hiT[k] * dxe, B0y = tcy[k] + hiT[k] * dye;
        float c_ = A0x * B0y - B0x * A0y;
        S += ((loT[k] < hiT[k]) && hullOK) ? c_ : 0.f;
    }
    float inter = fabsf(0.5f * S);

    float uni = areaA + areaB - inter;
    float giou = inter / fmaxf(uni, EPSF) - (areaC - uni) / fmaxf(areaC, EPSF);
    giou = fminf(1.f, fmaxf(-1.f, giou));   // true giou in (-1,1]: clamp only helps
    float loss = (1.f - giou) * w_i;
    float contrib = ((tid & 3) == 0 && valid) ? loss : 0.f;   // one lane per quad

    // ---- wave reduce -> cross-wave LDS reduce -> one atomic per block ----
#pragma unroll
    for (int off = 32; off > 0; off >>= 1) contrib += __shfl_down(contrib, off, 64);
    __syncthreads();                            // HH reads done before epilogue
    if ((tid & 63) == 0) red[tid >> 6] = contrib;
    __syncthreads();
    if (tid == 0) {
        float s = red[0] + red[1] + red[2] + red[3];
        atomicAdd(out, s * invN);               // one atomic per block, staggered
    }
}

extern "C" void kernel_launch(void* const* d_in, const int* in_sizes, int n_in,
                              void* d_out, int out_size, void* d_ws, size_t ws_size,
                              hipStream_t stream) {
    const float* pred = (const float*)d_in[0];
    const float* target = (const float*)d_in[1];
    const float* weight = (const float*)d_in[2];
    float* out = (float*)d_out;
    int n = in_sizes[2];  // weight has N elements

    int grid = (n + 63) / 64;  // 64 instances per 256-thread block (4 lanes each)
    giou_kernel<<<grid, 256, 0, stream>>>(pred, target, weight, out, n, 1.0f / (float)n);
}

// Round 3
// 72.987 us; speedup vs baseline: 1.0465x; 1.0465x over previous
//
#include <hip/hip_runtime.h>
#include <math.h>

#define EPSF 1e-9f

// r17 = r15 structure (2 lanes/instance, 128 inst/block) + clip-loop split
// across the lane pair. Evidence (r1/r2): kernel is ~3-4 us issue-bound vs a
// ~70 us fixed harness cost (268MB re-poison fill @41us + ~7 restore
// dispatches + graph gaps); occupancy doubling gave no win, so minimize
// issued ops. The S1/S2 clip loop was the only duplicated work across the
// pair: now even lane does edges 0,2,4.., odd lane 1,3,5..; S combined by
// shfl-add (commutative, both lanes bit-identical), loT/hiT by shfl max/min
// (order-free; sticky-kill (lo>=1,hi<=0) dominates max/min and killed
// intervals contribute exactly 0 under the lo<hi gate in any ordering).
__global__ __launch_bounds__(256)
void giou_kernel(const float* __restrict__ pred,
                 const float* __restrict__ target,
                 const float* __restrict__ weight,
                 float* __restrict__ out,
                 int n, float invN) {
    __shared__ float2 HH[9 * 256];            // even-lane hull(P) verts, [slot][tid]
    __shared__ float red[4];
    const int tid = threadIdx.x;
    const int odd = tid & 1;
    const int i0 = blockIdx.x * 128 + (tid >> 1);
    const bool valid = i0 < n;
    const int i = valid ? i0 : (n > 0 ? n - 1 : 0);

    // ---- target (4 pts) + instance centering at T centroid ----
    float Tx[4], Ty[4];
    {
        const float4* tp = (const float4*)target + (size_t)i * 2;
        float4 t0 = tp[0], t1 = tp[1];
        Tx[0] = t0.x; Ty[0] = t0.y; Tx[1] = t0.z; Ty[1] = t0.w;
        Tx[2] = t1.x; Ty[2] = t1.y; Tx[3] = t1.z; Ty[3] = t1.w;
    }
    float w_i = weight[i];                    // independent early load
    float ctrx = 0.25f * (Tx[0] + Tx[1] + Tx[2] + Tx[3]);
    float ctry = 0.25f * (Ty[0] + Ty[1] + Ty[2] + Ty[3]);
#pragma unroll
    for (int k = 0; k < 4; k++) { Tx[k] -= ctrx; Ty[k] -= ctry; }

    float saT = 0.5f * ((Tx[0] * Ty[1] - Tx[1] * Ty[0]) + (Tx[1] * Ty[2] - Tx[2] * Ty[1]) +
                        (Tx[2] * Ty[3] - Tx[3] * Ty[2]) + (Tx[3] * Ty[0] - Tx[0] * Ty[3]));
    float areaB = fabsf(saT);
    bool rev = saT < 0.f;
    float tcx[4], tcy[4];     // CCW target (centered)
#pragma unroll
    for (int k = 0; k < 4; k++) {
        tcx[k] = rev ? Tx[3 - k] : Tx[k];
        tcy[k] = rev ? Ty[3 - k] : Ty[k];
    }

    // ---- 13-pt working set (centered, registers) ----
    float X[13], Y[13];
    {
        const float2* pp = (const float2*)pred + (size_t)i * 9;
#pragma unroll
        for (int k = 0; k < 9; k++) {
            float2 v = pp[k];
            X[k] = v.x - ctrx; Y[k] = v.y - ctry;
        }
    }
#pragma unroll
    for (int k = 0; k < 4; k++) {
        X[9 + k] = odd ? Tx[k] : X[0];
        Y[9 + k] = odd ? Ty[k] : Y[0];
    }

    // ---- Jarvis march (CCW), tournament-tree candidate selection ----
    float sxm = X[0], sym = Y[0];
#pragma unroll
    for (int j = 1; j < 13; j++) {
        bool lt = (X[j] < sxm) || ((X[j] == sxm) && (Y[j] < sym));
        sxm = lt ? X[j] : sxm;
        sym = lt ? Y[j] : sym;
    }
    float cx = sxm, cy = sym;
    float area2 = 0.f;
    int h = 0;
    bool done = false;
#pragma unroll 1
    for (int step = 0; step < 13; step++) {
        if (__builtin_amdgcn_ballot_w64(!done) == 0ull) break;   // wave-uniform exit
        float ax[13], ay[13], rx[13], ry[13], dd[13];
#pragma unroll
        for (int j = 0; j < 13; j++) {
            ax[j] = X[j]; ay[j] = Y[j];
            rx[j] = X[j] - cx; ry[j] = Y[j] - cy;
            dd[j] = rx[j] * rx[j] + ry[j] * ry[j];   // 0 -> candidate == cur
        }
        // b beats a iff b valid && (a invalid || b CW of a || collinear+farther)
#define MATCH_(a, b)                                                          \
        {                                                                     \
            float cr_ = rx[a] * ry[b] - ry[a] * rx[b];                        \
            bool bw_ = (dd[b] > 0.f) &&                                       \
                       ((dd[a] == 0.f) || (cr_ < 0.f) ||                      \
                        ((cr_ == 0.f) && (dd[b] > dd[a])));                   \
            ax[a] = bw_ ? ax[b] : ax[a]; ay[a] = bw_ ? ay[b] : ay[a];         \
            rx[a] = bw_ ? rx[b] : rx[a]; ry[a] = bw_ ? ry[b] : ry[a];         \
            dd[a] = bw_ ? dd[b] : dd[a];                                      \
        }
        MATCH_(0, 1)  MATCH_(2, 3)  MATCH_(4, 5)
        MATCH_(6, 7)  MATCH_(8, 9)  MATCH_(10, 11)
        MATCH_(0, 2)  MATCH_(4, 6)  MATCH_(8, 10)
        MATCH_(0, 4)  MATCH_(8, 12)
        MATCH_(0, 8)
#undef MATCH_
        bool bv = dd[0] > 0.f;
        float bx = bv ? ax[0] : cx;
        float by = bv ? ay[0] : cy;
        if (!done) {
            if (!odd && h < 9) HH[h * 256 + tid] = make_float2(cx, cy);
            h++;
            area2 += cx * by - bx * cy;
        }
        done = done || ((bx == sxm) && (by == sym)) || ((bx == cx) && (by == cy));
        cx = bx; cy = by;
    }
    float area = fabsf(0.5f * area2);

    // ---- exchange areas / hull size ----
    float areaO = __shfl_xor(area, 1, 64);
    float areaA = odd ? areaO : area;
    float areaC = odd ? area : areaO;
    int hO = __shfl_xor(h, 1, 64);
    int mA = odd ? hO : h;                    // hull(P) vertex count
    mA = (mA < 9) ? mA : 9;                   // defensive (write guard matches)
    __syncthreads();                          // even-lane hull visible
    const float2* HP = &HH[tid & ~1];         // even column of the pair

    // ---- merged S1/S2 over hull(P) edges, SPLIT across the lane pair:
    //      even lane handles j=0,2,4.., odd lane j=1,3,5.. ----
    float S = 0.f;
    float loT[4] = {0.f, 0.f, 0.f, 0.f}, hiT[4] = {1.f, 1.f, 1.f, 1.f};
#pragma unroll 1
    for (int j = odd; j < mA; j += 2) {
        float2 a = HP[j * 256];
        int j1 = (j + 1 == mA) ? 0 : j + 1;
        float2 b = HP[j1 * 256];

        // --- S1 for hull edge a->b (Liang-Barsky vs T's 4 CCW planes) ---
        float lo = 0.f, hi = 1.f;
#pragma unroll
        for (int e = 0; e < 4; e++) {
            int e1 = (e + 1) & 3;
            float ex_ = tcx[e1] - tcx[e], ey_ = tcy[e1] - tcy[e];
            float s0 = ex_ * (a.y - tcy[e]) - ey_ * (a.x - tcx[e]);
            float s1 = ex_ * (b.y - tcy[e]) - ey_ * (b.x - tcx[e]);
            bool in0 = s0 >= 0.f, in1 = s1 >= 0.f;
            float den = s0 - s1;
            float ddn = (fabsf(den) < 1e-30f) ? 1e-30f : den;
            float t = s0 / ddn;                  // only used when in0!=in1
            bool crs = (in0 != in1);
            lo = (crs && !in0) ? fmaxf(lo, t) : lo;
            hi = (crs && in0)  ? fminf(hi, t) : hi;
            bool out2 = (!in0 && !in1);
            lo = out2 ? 1.f : lo;                // sticky kill
            hi = out2 ? 0.f : hi;
        }
        float dxe = b.x - a.x, dye = b.y - a.y;
        float A0x = a.x + lo * dxe, A0y = a.y + lo * dye;
        float B0x = a.x + hi * dxe, B0y = a.y + hi * dye;
        float c1_ = A0x * B0y - B0x * A0y;
        S += (lo < hi) ? c1_ : 0.f;

        // --- S2 interval updates for plane (a,b) ---
#pragma unroll
        for (int k = 0; k < 4; k++) {
            int k1 = (k + 1) & 3;
            float s0 = dxe * (tcy[k] - a.y) - dye * (tcx[k] - a.x);
            float s1 = dxe * (tcy[k1] - a.y) - dye * (tcx[k1] - a.x);
            bool in0 = s0 >= 0.f, in1 = s1 >= 0.f;
            float den = s0 - s1;
            float ddn = (fabsf(den) < 1e-30f) ? 1e-30f : den;
            float t = s0 / ddn;
            bool crs = (in0 != in1);
            loT[k] = (crs && !in0) ? fmaxf(loT[k], t) : loT[k];
            hiT[k] = (crs && in0)  ? fminf(hiT[k], t) : hiT[k];
            bool out2 = (!in0 && !in1);
            loT[k] = out2 ? 1.f : loT[k];
            hiT[k] = out2 ? 0.f : hiT[k];
        }
    }
    // ---- combine pair-split partials (both lanes end with identical values) ----
    S += __shfl_xor(S, 1, 64);
#pragma unroll
    for (int k = 0; k < 4; k++) {
        loT[k] = fmaxf(loT[k], __shfl_xor(loT[k], 1, 64));
        hiT[k] = fminf(hiT[k], __shfl_xor(hiT[k], 1, 64));
    }
    bool hullOK = (mA >= 3);                    // mA<3: inter == 0 exactly
#pragma unroll
    for (int k = 0; k < 4; k++) {
        int k1 = (k + 1) & 3;
        float dxe = tcx[k1] - tcx[k], dye = tcy[k1] - tcy[k];
        float A0x = tcx[k] + loT[k] * dxe, A0y = tcy[k] + loT[k] * dye;
        float B0x = tcx[k] + hiT[k] * dxe, B0y = tcy[k] + hiT[k] * dye;
        float c_ = A0x * B0y - B0x * A0y;
        S += ((loT[k] < hiT[k]) && hullOK) ? c_ : 0.f;
    }
    float inter = fabsf(0.5f * S);

    float uni = areaA + areaB - inter;
    float giou = inter / fmaxf(uni, EPSF) - (areaC - uni) / fmaxf(areaC, EPSF);
    giou = fminf(1.f, fmaxf(-1.f, giou));   // true giou in (-1,1]: clamp only helps
    float loss = (1.f - giou) * w_i;
    float contrib = (!odd && valid) ? loss : 0.f;

    // ---- wave reduce -> cross-wave LDS reduce -> one atomic per block ----
#pragma unroll
    for (int off = 32; off > 0; off >>= 1) contrib += __shfl_down(contrib, off, 64);
    __syncthreads();                            // HH reads done before epilogue
    if ((tid & 63) == 0) red[tid >> 6] = contrib;
    __syncthreads();
    if (tid == 0) {
        float s = red[0] + red[1] + red[2] + red[3];
        atomicAdd(out, s * invN);               // 256 atomics total, staggered
    }
}

extern "C" void kernel_launch(void* const* d_in, const int* in_sizes, int n_in,
                              void* d_out, int out_size, void* d_ws, size_t ws_size,
                              hipStream_t stream) {
    const float* pred = (const float*)d_in[0];
    const float* target = (const float*)d_in[1];
    const float* weight = (const float*)d_in[2];
    float* out = (float*)d_out;
    int n = in_sizes[2];  // weight has N elements

    int grid = (n + 127) / 128;  // 128 instances per 256-thread block
    giou_kernel<<<grid, 256, 0, stream>>>(pred, target, weight, out, n, 1.0f / (float)n);
}